// Round 11
// baseline (177.013 us; speedup 1.0000x reference)
//
#include <hip/hip_runtime.h>
#include <hip/hip_bf16.h>

// HypoNerf fused MLP on MI355X (gfx950). R11 = R10 + 32x32x16 MFMA.
//  16x16x32 runs at 2075 TF ceiling; 32x32x16 at 2382-2495 TF (m06/m119):
//  -17% MFMA pipe time and half the MFMA instruction count for the same
//  math. acc = 4 x f32x16 (64 regs, unchanged); weights re-packed per
//  (kt, nt, kh) 1KB fragments; h reads remain 4 x b128 per kt via parity
//  bases. C/D layout per m74/m101: col=lane&31, row=(reg&3)+8(reg>>2)+4hi.
//  Everything else from R10: MT=64, 3 waves/SIMD, pointer-advance streams,
//  folded final projection, raw barriers, XCD swizzle.

#define H 256
#define MT 64
#define PE_NF 60

typedef __attribute__((ext_vector_type(8))) short s16x8;    // 8 bf16
typedef __attribute__((ext_vector_type(4))) float f32x4;
typedef __attribute__((ext_vector_type(16))) float f32x16;  // 32x32 acc

static __device__ __forceinline__ unsigned short f2bf(float v) {
  unsigned int u = __float_as_uint(v);
  return (unsigned short)((u + 0x7FFFu + ((u >> 16) & 1u)) >> 16);
}
// swizzled 16B-chunk index within a 256-elem (32-chunk) row
static __device__ __forceinline__ int hswz(int row, int chunk) {
  return (chunk & ~7) | ((chunk ^ row) & 7);
}

static __device__ __forceinline__ void bar_raw() {
  asm volatile("s_barrier" ::: "memory");
}
static __device__ __forceinline__ void bar_lgkm() {
  asm volatile("s_waitcnt lgkmcnt(0)\n\ts_barrier" ::: "memory");
}

// ---------------------------------------------------------------------------
// Prep: wb (fp32, [K+1][H], last row bias) -> fragment-packed bf16 for
// 32x32x16.  frag id = (kt*8 + nt)*2 + kh  (kt=k>>5, nt=n>>5, kh=(k>>4)&1),
// within frag: lane = (n&31) + ((k>>3)&1)*32, elem j = k&7.  1KB/frag.
// ---------------------------------------------------------------------------
__global__ __launch_bounds__(256) void prep_weights(
    const float* __restrict__ wb0, const float* __restrict__ wb1,
    const float* __restrict__ wb2, const float* __restrict__ wb3,
    const float* __restrict__ wb4,
    unsigned short* __restrict__ w0p, unsigned short* __restrict__ w14p,
    float* __restrict__ biases) {
  int z = blockIdx.z;
  int li = z >> 4, b = z & 15;
  int k0 = blockIdx.x * 32;
  int n0 = blockIdx.y * 32;
  int Ks;
  const float* src;
  unsigned short* dst;
  if (li == 0) {
    Ks = 120;
    if (k0 >= 128) return;
    src = wb0 + (size_t)b * 121 * H;
    dst = w0p + (size_t)b * 32768;
  } else {
    Ks = 256;
    const float* srcs[4] = {wb1, wb2, wb3, wb4};
    src = srcs[li - 1] + (size_t)b * 257 * H;
    dst = w14p + ((size_t)(li - 1) * 16 + b) * 65536;
  }
  __shared__ float tile[32][33];
  int t = threadIdx.x;
  int tx = t & 31, ty = t >> 5;
#pragma unroll
  for (int i = 0; i < 4; ++i) {
    int k = k0 + ty + i * 8;
    tile[ty + i * 8][tx] = (k < Ks) ? src[(size_t)k * H + n0 + tx] : 0.f;
  }
  if (k0 == 0 && ty == 0)
    biases[((size_t)li * 16 + b) * H + n0 + tx] = src[(size_t)Ks * H + n0 + tx];
  __syncthreads();
  if (t < 128) {
    int nn = t & 31, kg = t >> 5;           // kg: 8-elem k group 0..3
    int kt = k0 >> 5, nt = n0 >> 5;
    int kh = kg >> 1;
    int lane = nn + (kg & 1) * 32;
    int frag = (kt * 8 + nt) * 2 + kh;
    union { unsigned short us[8]; s16x8 v; } pk;
#pragma unroll
    for (int j = 0; j < 8; ++j) pk.us[j] = f2bf(tile[kg * 8 + j][nn]);
    *(s16x8*)&dst[(size_t)frag * 512 + lane * 8] = pk.v;
  }
}

// ---------------------------------------------------------------------------
// One fused Linear+ReLU layer, 32x32x16 MFMA. Wave wc: 64 rows x cols
// [wc*64,+64) as 2x2 tiles of 32x32.
// A (weights): lane holds W^T[wc*64+ntl*32+(l&31)][kt*32+kh*16+hi*8 ..+7]
// B (h):       lane holds h[mt*32+(l&31)][same k]
// D: col = m-tile + (l&31); row n' = (reg&3)+8*(reg>>2)+4*hi  [m74/m101]
// fpb advanced +16KB per kt; frag imm offsets (ntl*2+kh)*1024.
// ---------------------------------------------------------------------------
template <int NKT, bool LAST>
static __device__ __forceinline__ void mlp_layer(
    const char* fpb, const char* fpn, const float* __restrict__ bl,
    unsigned short* __restrict__ h_s, const float* __restrict__ wout_s,
    const int m32, const int hi, const int wc, const int l,
    s16x8 (&wf)[2][4], float* psum) {
  static_assert((NKT & 1) == 0, "ping-pong parity needs even NKT");

  // acc[mt][ntl] init = bias[wc*64 + ntl*32 + (reg&3)+8*(reg>>2)+4*hi]
  f32x16 acc[2][2];
#pragma unroll
  for (int ntl = 0; ntl < 2; ++ntl)
#pragma unroll
    for (int q = 0; q < 4; ++q) {
      f32x4 bq = *(const f32x4*)(bl + wc * 64 + ntl * 32 + q * 8 + hi * 4);
#pragma unroll
      for (int s = 0; s < 4; ++s) {
        acc[0][ntl][q * 4 + s] = bq[s];
        acc[1][ntl][q * 4 + s] = bq[s];
      }
    }

  // h ds_read bases per (kt-parity, kh); chunk = 4p + 2kh + hi (swz within 8)
  const char* hb = (const char*)h_s;
  unsigned ab[2][2];
#pragma unroll
  for (int p = 0; p < 2; ++p)
#pragma unroll
    for (int kh = 0; kh < 2; ++kh)
      ab[p][kh] = m32 * 512 + (((4 * p + 2 * kh + hi) ^ (m32 & 7)) & 7) * 16;

  // h fragments, double-buffered by kt parity: af[p][mt*2+kh]
  s16x8 af[2][4];
#pragma unroll
  for (int mt = 0; mt < 2; ++mt)
#pragma unroll
    for (int kh = 0; kh < 2; ++kh)
      af[0][mt * 2 + kh] = *(const s16x8*)(hb + ab[0][kh] + mt * 16384);

#pragma unroll
  for (int kt = 0; kt < NKT; ++kt) {
    if (kt + 1 < NKT) {
      fpb += 16384;   // 16 frags x 1KB -> next kt
#pragma unroll
      for (int c = 0; c < 4; ++c)
        wf[(kt + 1) & 1][c] = *(const s16x8*)(fpb + c * 1024);
      const int p1 = (kt + 1) & 1;
      const unsigned off = ((kt + 1) >> 1) * 128;
#pragma unroll
      for (int mt = 0; mt < 2; ++mt)
#pragma unroll
        for (int kh = 0; kh < 2; ++kh)
          af[p1][mt * 2 + kh] =
              *(const s16x8*)(hb + ab[p1][kh] + off + mt * 16384);
    } else if (!LAST) {
#pragma unroll
      for (int c = 0; c < 4; ++c)
        wf[0][c] = *(const s16x8*)(fpn + c * 1024);   // NKT even -> slot 0
    }
    __builtin_amdgcn_s_setprio(1);
#pragma unroll
    for (int mt = 0; mt < 2; ++mt)
#pragma unroll
      for (int ntl = 0; ntl < 2; ++ntl)
#pragma unroll
        for (int kh = 0; kh < 2; ++kh)
          acc[mt][ntl] = __builtin_amdgcn_mfma_f32_32x32x16_bf16(
              wf[kt & 1][ntl * 2 + kh], af[kt & 1][mt * 2 + kh],
              acc[mt][ntl], 0, 0, 0);
    __builtin_amdgcn_s_setprio(0);
  }

  if constexpr (LAST) {
    // folded projection: lane covers rows m = mt*32+m32, its 16 n per tile
    float p[2];
#pragma unroll
    for (int mt = 0; mt < 2; ++mt) {
      float s = 0.f;
#pragma unroll
      for (int ntl = 0; ntl < 2; ++ntl)
#pragma unroll
        for (int q = 0; q < 4; ++q) {
          f32x4 wv = *(const f32x4*)(wout_s + wc * 64 + ntl * 32 + q * 8 + hi * 4);
#pragma unroll
          for (int s2 = 0; s2 < 4; ++s2)
            s += fmaxf(acc[mt][ntl][q * 4 + s2], 0.f) * wv[s2];
        }
      s += __shfl_xor(s, 32);   // combine hi halves (same m, other n half)
      p[mt] = s;
    }
    if (l < 32) {
      psum[wc * 64 + l]      = p[0];
      psum[wc * 64 + 32 + l] = p[1];
    }
  } else {
    bar_raw();   // h reads consumed by MFMAs; vmcnt NOT drained
    // epilogue: ReLU + pack 4 bf16 -> b64 store  h[m][n0..n0+3]
#pragma unroll
    for (int mt = 0; mt < 2; ++mt) {
      const int m = mt * 32 + m32;
      const int rowb = m * 256;
#pragma unroll
      for (int ntl = 0; ntl < 2; ++ntl)
#pragma unroll
        for (int q = 0; q < 4; ++q) {
          const int cs = hswz(m, wc * 8 + ntl * 4 + q);
          float v0 = fmaxf(acc[mt][ntl][q * 4 + 0], 0.f);
          float v1 = fmaxf(acc[mt][ntl][q * 4 + 1], 0.f);
          float v2 = fmaxf(acc[mt][ntl][q * 4 + 2], 0.f);
          float v3 = fmaxf(acc[mt][ntl][q * 4 + 3], 0.f);
          union { __hip_bfloat162 h2[2]; uint2 u; } pk;
          pk.h2[0] = __float22bfloat162_rn(float2{v0, v1});
          pk.h2[1] = __float22bfloat162_rn(float2{v2, v3});
          *(uint2*)&h_s[rowb + cs * 8 + hi * 4] = pk.u;
        }
    }
    bar_lgkm();  // DS writes visible; vmcnt untouched
  }
}

// ---------------------------------------------------------------------------
__global__ __launch_bounds__(256, 3) void hyponerf_main(
    const float* __restrict__ x, const float* __restrict__ rfreq,
    const float* __restrict__ wbout,
    const unsigned short* __restrict__ w0p, const unsigned short* __restrict__ w14p,
    const float* __restrict__ biases, float* __restrict__ out) {
  __shared__ __align__(16) unsigned short h_s[MT * 256];  // 32768 B
  __shared__ float fr_s[PE_NF * 3];
  __shared__ float x_s[MT * 3];
  __shared__ float wout_s[H + 1];
  __shared__ float psum[4 * 64];

  // XCD-aware swizzle: 4096 blocks, 8 XCDs -> contiguous batches per XCD
  int bid = blockIdx.x;
  int logical = (bid & 7) * 512 + (bid >> 3);
  int b  = logical >> 8;
  int mt = logical & 255;

  int t = threadIdx.x;
  int wc = t >> 6, l = t & 63;
  int m32 = l & 31;
  int hi  = l >> 5;

  // fragment stream bases (wave-col + lane offsets), bytes
  const size_t lane_off = (size_t)wc * 4096 + (size_t)l * 16;
  const char* f0 = (const char*)(w0p + (size_t)b * 32768) + lane_off;
  const char* f1 = (const char*)(w14p + (size_t)(0 * 16 + b) * 65536) + lane_off;
  const char* f2 = (const char*)(w14p + (size_t)(1 * 16 + b) * 65536) + lane_off;
  const char* f3 = (const char*)(w14p + (size_t)(2 * 16 + b) * 65536) + lane_off;
  const char* f4 = (const char*)(w14p + (size_t)(3 * 16 + b) * 65536) + lane_off;

  // issue layer0 kt0 weight frags NOW; hides under staging + PE
  s16x8 wf[2][4];
#pragma unroll
  for (int c = 0; c < 4; ++c) wf[0][c] = *(const s16x8*)(f0 + c * 1024);

  const float* xg = x + ((size_t)b * 16384 + (size_t)mt * MT) * 3;
  for (int i = t; i < MT * 3; i += 256) x_s[i] = xg[i];
  for (int i = t; i < PE_NF * 3; i += 256) fr_s[i] = rfreq[i] * 20.0f;
  for (int i = t; i < H + 1; i += 256) wout_s[i] = wbout[(size_t)b * (H + 1) + i];
  bar_lgkm();   // staging visible; vmcnt NOT drained

  // ---- Gaussian PE, chunk-owned b128 stores: thread (r = t>>2, q = t&3)
  {
    int r = t >> 2;
    int q = t & 3;
    float x0 = x_s[r * 3 + 0], x1 = x_s[r * 3 + 1], x2 = x_s[r * 3 + 2];
    int rowb = r * 256;
#pragma unroll
    for (int cc = 0; cc < 4; ++cc) {
      int ch = q * 4 + cc;
      union { unsigned short us[8]; s16x8 v; } pk;
#pragma unroll
      for (int j = 0; j < 8; ++j) {
        int n = ch * 8 + j;
        float v = 0.f;
        if (n < 60) {
          float kv = x0 * fr_s[n * 3] + x1 * fr_s[n * 3 + 1] + x2 * fr_s[n * 3 + 2];
          v = __sinf(kv);
        } else if (n < 120) {
          int f = n - 60;
          float kv = x0 * fr_s[f * 3] + x1 * fr_s[f * 3 + 1] + x2 * fr_s[f * 3 + 2];
          v = __cosf(kv);
        }
        pk.us[j] = f2bf(v);
      }
      *(s16x8*)&h_s[rowb + hswz(r, ch) * 8] = pk.v;
    }
  }
  bar_lgkm();   // PE writes visible; layer0 frags still in flight

  // ---- 5 fused Linear+ReLU layers (wf carries next layer's kt0 frags)
  const float* bb = biases + (size_t)b * H;
  mlp_layer<4, false>(f0, f1, bb + 0 * 16 * H, h_s, wout_s, m32, hi, wc, l,
                      wf, psum);
  mlp_layer<8, false>(f1, f2, bb + 1 * 16 * H, h_s, wout_s, m32, hi, wc, l,
                      wf, psum);
  mlp_layer<8, false>(f2, f3, bb + 2 * 16 * H, h_s, wout_s, m32, hi, wc, l,
                      wf, psum);
  mlp_layer<8, false>(f3, f4, bb + 3 * 16 * H, h_s, wout_s, m32, hi, wc, l,
                      wf, psum);
  mlp_layer<8, true >(f4, f4, bb + 4 * 16 * H, h_s, wout_s, m32, hi, wc, l,
                      wf, psum);

  // ---- gather: out[r] = sum_wc psum[wc][r] + bias_out
  bar_lgkm();
  if (t < MT) {
    float s = psum[t] + psum[64 + t] + psum[128 + t] + psum[192 + t];
    out[(size_t)b * 16384 + (size_t)mt * MT + t] = s + wout_s[H];
  }
}

// ---------------------------------------------------------------------------
extern "C" void kernel_launch(void* const* d_in, const int* in_sizes, int n_in,
                              void* d_out, int out_size, void* d_ws, size_t ws_size,
                              hipStream_t stream) {
  const float* x     = (const float*)d_in[0];
  const float* wb0   = (const float*)d_in[1];
  const float* wb1   = (const float*)d_in[2];
  const float* wb2   = (const float*)d_in[3];
  const float* wb3   = (const float*)d_in[4];
  const float* wb4   = (const float*)d_in[5];
  const float* wbout = (const float*)d_in[6];
  const float* rfreq = (const float*)d_in[7];
  float* out = (float*)d_out;

  char* ws = (char*)d_ws;
  unsigned short* w0p  = (unsigned short*)ws;                                // 16 x 32768 bf16
  unsigned short* w14p = (unsigned short*)(ws + (size_t)16 * 32768 * 2);     // 64 x 65536 bf16
  float* biases = (float*)(ws + (size_t)16 * 32768 * 2
                              + (size_t)64 * 65536 * 2);                     // [5][16][256] f32

  prep_weights<<<dim3(8, 8, 80), 256, 0, stream>>>(wb0, wb1, wb2, wb3, wb4,
                                                   w0p, w14p, biases);
  hyponerf_main<<<dim3(4096), 256, 0, stream>>>(x, rfreq, wbout, w0p, w14p,
                                                biases, out);
}